// Round 8
// baseline (240.090 us; speedup 1.0000x reference)
//
#include <hip/hip_runtime.h>
#include <cstdint>
#include <math.h>

// ---------------------------------------------------------------------------
// CausalSelfAttention (B=4, T=2048, D=1024, H=16, Dh=64), fp32 in/out,
// bf16 MFMA compute internally.
// Pipeline: fused cast -> fused QKV GEMM (NEW: 256x256 tile, BK=64, 4-phase
//           read-ahead counted-lgkm schedule, vmcnt(4) depth pipeline,
//           384 blocks) -> flash attention (key-split + setprio, round 7)
//           -> output projection (128x256 read-ahead, round 4/7).
//
// Round-8 rationale: QKV at 31% MfmaUtil is bound by serialized LDS service
// + MFMA per phase. 256^2 tile cuts reads/MFMA 0.417->0.375 and grows the
// per-phase MFMA cluster 12->16 so the read-ahead window covers LDS service.
// Staging ledger: per tile ph0 stages Ah1(t+1), ph1 Ah0(t+2), ph2 B01(t+2),
// ph3 B23(t+2); each overwritten half dies >=1 barrier earlier; vmcnt(4) at
// ph2 proves t+1 landed before ph3's cross-buffer read-ahead.
// ---------------------------------------------------------------------------

typedef unsigned short u16;
typedef __bf16 bf16x8 __attribute__((ext_vector_type(8)));
typedef __bf16 bf16x4 __attribute__((ext_vector_type(4)));
typedef float f32x4 __attribute__((ext_vector_type(4)));

__device__ __forceinline__ u16 f32_bf16(float f) {  // round-nearest-even
  union { float f; uint32_t u; } c; c.f = f;
  uint32_t u = c.u;
  return (u16)((u + 0x7FFFu + ((u >> 16) & 1u)) >> 16);
}

__device__ __forceinline__ f32x4 mfma16(bf16x8 a, bf16x8 b, f32x4 c) {
  return __builtin_amdgcn_mfma_f32_16x16x32_bf16(a, b, c, 0, 0, 0);
}

// async global->LDS, 16B/lane. LDS dest must be wave-uniform base + lane*16.
__device__ __forceinline__ void gload_lds16(const u16* g, u16* l) {
  __builtin_amdgcn_global_load_lds(
      (const __attribute__((address_space(1))) void*)g,
      (__attribute__((address_space(3))) void*)l, 16, 0, 0);
}

template <int N>
__device__ __forceinline__ void wait_lgkm() {
  if (N == 0)       asm volatile("s_waitcnt lgkmcnt(0)" ::: "memory");
  else if (N == 4)  asm volatile("s_waitcnt lgkmcnt(4)" ::: "memory");
  else if (N == 8)  asm volatile("s_waitcnt lgkmcnt(8)" ::: "memory");
  else if (N == 10) asm volatile("s_waitcnt lgkmcnt(10)" ::: "memory");
  else if (N == 12) asm volatile("s_waitcnt lgkmcnt(12)" ::: "memory");
  __builtin_amdgcn_sched_barrier(0);
}
template <int N>
__device__ __forceinline__ void wait_vm() {
  if (N == 6)      asm volatile("s_waitcnt vmcnt(6)" ::: "memory");
  else if (N == 4) asm volatile("s_waitcnt vmcnt(4)" ::: "memory");
  else if (N == 2) asm volatile("s_waitcnt vmcnt(2)" ::: "memory");
  else if (N == 0) asm volatile("s_waitcnt vmcnt(0)" ::: "memory");
  __builtin_amdgcn_sched_barrier(0);
}

// barrier that does NOT drain the newest 2 vm loads (attn t+2 prefetch)
__device__ __forceinline__ void barrier_vm2() {
  asm volatile("s_waitcnt vmcnt(2)" ::: "memory");
  __builtin_amdgcn_sched_barrier(0);
  __builtin_amdgcn_s_barrier();
}

// ---------------------------------------------------------------------------
// fused cast fp32->bf16 of x + 4 weights into contiguous ws region
// ---------------------------------------------------------------------------
__global__ __launch_bounds__(256) void cvt_all_kernel(
    const float* __restrict__ x,
    const float* __restrict__ wq, const float* __restrict__ wk,
    const float* __restrict__ wv, const float* __restrict__ wo,
    u16* __restrict__ dst, int n_x, int n_w) {
  int i = blockIdx.x * 256 + threadIdx.x;
  const float* src;
  int off;
  if (i < n_x) { src = x; off = i; }
  else {
    int j = i - n_x;
    int w = j / n_w;  off = j - w * n_w;
    src = (w == 0) ? wq : (w == 1) ? wk : (w == 2) ? wv : wo;
  }
  float4 f = ((const float4*)src)[off];
  ushort4 o;
  o.x = f32_bf16(f.x); o.y = f32_bf16(f.y);
  o.z = f32_bf16(f.z); o.w = f32_bf16(f.w);
  ((ushort4*)dst)[i] = o;
}

// ---------------------------------------------------------------------------
// QKV GEMM: 256x256 tile, BK=64, 512 threads = 8 waves (2M x 4N), per-wave
// 128x64, acc[8][4]. LDS 128 KB: As[2][256*64] + Bs[2][256*64].
// C[m,n] = sum_k A[m,k]*B[n,k], B = [wq;wk;wv] rows; epilogue routes each
// 16-col subtile to Q (scaled log2e/8), K, or Vt (transposed).
//
// 4-phase read-ahead (round-4 schedule generalized), per K-tile t (buf c):
//  ph0: issue ds bfB(4)+afB(8) [cur]; stage Ah1(t+1) -> buf c^1;
//       lgkm(12) drains prev-ph3's afA(8)+bfA(4); MFMA m0-3 x n0-1; BAR
//  ph1: stage Ah0(t+2) -> buf c; lgkm(8) drains bfB; MFMA m0-3 x n2-3; BAR
//  ph2: stage B01(t+2) -> buf c; vmcnt(4) [Ah1(t+1) + older landed ->
//       t+1 complete]; lgkm(0); MFMA m4-7 x n0-1; BAR (globalizes vmcnt)
//  ph3: issue ds afA,bfA (t+1, buf c^1; safe after ph2 vmcnt+BAR);
//       sched_barrier; stage B23(t+2) -> buf c; MFMA m4-7 x n2-3; BAR
// Death ledger: Ah0(t) dead after ph0-BAR (staged ph1); B rows 0-127 dead
// after ph1-BAR (staged ph2); B128-255 after ph1 (staged ph3); Ah1(t) dead
// after ph2-BAR (staged at t+1's ph0). All stages >= 1 barrier after death.
// Tail: t=14: ph0 stage Ah1(15) only, vmcnt(0)@ph2; t=15: no stages/reads.
// LDS swizzle (verified rounds 1-7, 0 conflicts): row-local XOR, unchanged.
// ---------------------------------------------------------------------------
template <bool S0, bool S123, int VM, bool RD>
__device__ __forceinline__ void kq(
    f32x4 (&acc)[8][4], bf16x8 (&afA)[4][2], bf16x8 (&bfA)[2][2],
    const u16* __restrict__ aCur, const u16* __restrict__ bCur,
    const u16* __restrict__ aNx, const u16* __restrict__ bNx,
    u16* aStgN1, u16* aStg, u16* bStg,
    const u16* gaN1, const u16* gaN2, const u16* gbN2,
    int tid, int aoff0, int aoff1, int boff0, int boff1) {
  bf16x8 afB[4][2], bfB[2][2];

  // ---- phase 0: MFMA (m0-3 x n0-1) ----
#pragma unroll
  for (int nn = 0; nn < 2; ++nn) {  // bfB FIRST (ph1's lgkm(8) drains it)
    bfB[nn][0] = *(const bf16x8*)(bCur + boff0 + (2 + nn) * 1024);
    bfB[nn][1] = *(const bf16x8*)(bCur + boff1 + (2 + nn) * 1024);
  }
#pragma unroll
  for (int mm = 0; mm < 4; ++mm) {
    afB[mm][0] = *(const bf16x8*)(aCur + aoff0 + 4096 + mm * 1024);
    afB[mm][1] = *(const bf16x8*)(aCur + aoff1 + 4096 + mm * 1024);
  }
  if (S0) {  // Ah1(t+1) -> other buf: rows 64-127 (L1), 192-255 (L3)
    gload_lds16(gaN1 + 65536, aStgN1 + 4096 + tid * 8);
    gload_lds16(gaN1 + 196608, aStgN1 + 12288 + tid * 8);
  }
  wait_lgkm<12>();  // drains prev-ph3's afA+bfA; leaves bfB+afB (12)
  __builtin_amdgcn_s_setprio(1);
#pragma unroll
  for (int mm = 0; mm < 4; ++mm)
#pragma unroll
    for (int nn = 0; nn < 2; ++nn) {
      acc[mm][nn] = mfma16(afA[mm][0], bfA[nn][0], acc[mm][nn]);
      acc[mm][nn] = mfma16(afA[mm][1], bfA[nn][1], acc[mm][nn]);
    }
  __builtin_amdgcn_s_setprio(0);
  __builtin_amdgcn_s_barrier();

  // ---- phase 1: MFMA (m0-3 x n2-3) ----
  if (S123) {  // Ah0(t+2): rows 0-63 (L0), 128-191 (L2)
    gload_lds16(gaN2, aStg + tid * 8);
    gload_lds16(gaN2 + 131072, aStg + 8192 + tid * 8);
  }
  wait_lgkm<8>();  // drains bfB; leaves afB (8)
  __builtin_amdgcn_s_setprio(1);
#pragma unroll
  for (int mm = 0; mm < 4; ++mm)
#pragma unroll
    for (int nn = 0; nn < 2; ++nn) {
      acc[mm][2 + nn] = mfma16(afA[mm][0], bfB[nn][0], acc[mm][2 + nn]);
      acc[mm][2 + nn] = mfma16(afA[mm][1], bfB[nn][1], acc[mm][2 + nn]);
    }
  __builtin_amdgcn_s_setprio(0);
  __builtin_amdgcn_s_barrier();

  // ---- phase 2: MFMA (m4-7 x n0-1) ----
  if (S123) {  // B01(t+2): rows 0-63 (L0), 64-127 (L1)
    gload_lds16(gbN2, bStg + tid * 8);
    gload_lds16(gbN2 + 65536, bStg + 4096 + tid * 8);
  }
  if (VM >= 0) wait_vm<(VM >= 0 ? VM : 0)>();  // t+1 landed (per wave)
  wait_lgkm<0>();
  __builtin_amdgcn_s_setprio(1);
#pragma unroll
  for (int mm = 0; mm < 4; ++mm)
#pragma unroll
    for (int nn = 0; nn < 2; ++nn) {
      acc[4 + mm][nn] = mfma16(afB[mm][0], bfA[nn][0], acc[4 + mm][nn]);
      acc[4 + mm][nn] = mfma16(afB[mm][1], bfA[nn][1], acc[4 + mm][nn]);
    }
  __builtin_amdgcn_s_setprio(0);
  __builtin_amdgcn_s_barrier();  // globalizes vmcnt before ph3 reads

  // ---- phase 3: read-ahead t+1; MFMA (m4-7 x n2-3) ----
  if (RD) {
#pragma unroll
    for (int mm = 0; mm < 4; ++mm) {  // afA first, then bfA (ph0 drains 12)
      afA[mm][0] = *(const bf16x8*)(aNx + aoff0 + mm * 1024);
      afA[mm][1] = *(const bf16x8*)(aNx + aoff1 + mm * 1024);
    }
#pragma unroll
    for (int nn = 0; nn < 2; ++nn) {
      bfA[nn][0] = *(const bf16x8*)(bNx + boff0 + nn * 1024);
      bfA[nn][1] = *(const bf16x8*)(bNx + boff1 + nn * 1024);
    }
    __builtin_amdgcn_sched_barrier(0);  // reads stay issued before this MFMA
  }
  if (S123) {  // B23(t+2): rows 128-191 (L2), 192-255 (L3)
    gload_lds16(gbN2 + 131072, bStg + 8192 + tid * 8);
    gload_lds16(gbN2 + 196608, bStg + 12288 + tid * 8);
  }
  __builtin_amdgcn_s_setprio(1);
#pragma unroll
  for (int mm = 0; mm < 4; ++mm)
#pragma unroll
    for (int nn = 0; nn < 2; ++nn) {
      acc[4 + mm][2 + nn] = mfma16(afB[mm][0], bfB[nn][0], acc[4 + mm][2 + nn]);
      acc[4 + mm][2 + nn] = mfma16(afB[mm][1], bfB[nn][1], acc[4 + mm][2 + nn]);
    }
  __builtin_amdgcn_s_setprio(0);
  __builtin_amdgcn_s_barrier();
}

__global__ __launch_bounds__(512, 2) void qkv256(
    const u16* __restrict__ A, const u16* __restrict__ Bc,
    u16* __restrict__ Qb, u16* __restrict__ Kb, u16* __restrict__ Vt,
    float qscale) {
  constexpr int K = 1024;
  __shared__ u16 As[2][16384];  // [dbuf][256 rows x 64 k]
  __shared__ u16 Bs[2][16384];

  // XCD-bijective: per XCD 4 row-strips x 12 col-tiles (384 blocks)
  const int ord = blockIdx.x;
  const int xcd = ord & 7, g = ord >> 3;    // g in [0,48)
  const int rt = xcd * 4 + (g & 3);         // [0,32)
  const int ct = g >> 2;                    // [0,12)
  const int colm = ct * 256;
  const int row0 = rt * 256;

  const int tid = threadIdx.x;
  const int lane = tid & 63, wid = tid >> 6;
  const int quad = lane >> 4, l15 = lane & 15;
  const int wm = wid >> 2, wn = wid & 3;

  // staging: linear LDS dest, pre-swizzled global source
  const int srow = tid >> 3;                 // [0,64)
  const int selem = ((tid & 7) ^ (srow & 7)) * 8;
  const u16* ga = A + (size_t)(row0 + srow) * K + selem;
  const u16* gb = Bc + (size_t)(colm + srow) * K + selem;

  u16* pA0 = &As[0][0];
  u16* pA1 = &As[1][0];
  u16* pB0 = &Bs[0][0];
  u16* pB1 = &Bs[1][0];

  // swizzled fragment read offsets (elements); row-local swizzle unchanged
  const int swz = 8 * (quad ^ (l15 & 3));
  const int kof = 32 * ((l15 >> 2) & 1);
  const int aoff0 = (wm * 128 + l15) * 64 + swz + kof;
  const int aoff1 = (wm * 128 + l15) * 64 + swz + (32 - kof);
  const int boff0 = (wn * 64 + l15) * 64 + swz + kof;
  const int boff1 = (wn * 64 + l15) * 64 + swz + (32 - kof);

  f32x4 acc[8][4];
  const f32x4 zero = {0.f, 0.f, 0.f, 0.f};
#pragma unroll
  for (int m = 0; m < 8; ++m)
#pragma unroll
    for (int n = 0; n < 4; ++n) acc[m][n] = zero;

  bf16x8 afA[4][2], bfA[2][2];

  // prologue: tile0 full (8 loads) + tile1 {Ah0,B01,B23} (6 loads);
  // Ah1(1) is staged uniformly at tile0's ph0. vmcnt(6) -> tile0 landed.
  gload_lds16(ga, pA0 + tid * 8);
  gload_lds16(ga + 131072, pA0 + 8192 + tid * 8);
  gload_lds16(ga + 65536, pA0 + 4096 + tid * 8);
  gload_lds16(ga + 196608, pA0 + 12288 + tid * 8);
  gload_lds16(gb, pB0 + tid * 8);
  gload_lds16(gb + 65536, pB0 + 4096 + tid * 8);
  gload_lds16(gb + 131072, pB0 + 8192 + tid * 8);
  gload_lds16(gb + 196608, pB0 + 12288 + tid * 8);
  gload_lds16(ga + 64, pA1 + tid * 8);
  gload_lds16(ga + 64 + 131072, pA1 + 8192 + tid * 8);
  gload_lds16(gb + 64, pB1 + tid * 8);
  gload_lds16(gb + 64 + 65536, pB1 + 4096 + tid * 8);
  gload_lds16(gb + 64 + 131072, pB1 + 8192 + tid * 8);
  gload_lds16(gb + 64 + 196608, pB1 + 12288 + tid * 8);
  wait_vm<6>();
  __builtin_amdgcn_s_barrier();

  // pre-issue tile-0 ph0 fragments (afA, bfA) — plays prev-ph3's role
#pragma unroll
  for (int mm = 0; mm < 4; ++mm) {
    afA[mm][0] = *(const bf16x8*)(pA0 + aoff0 + mm * 1024);
    afA[mm][1] = *(const bf16x8*)(pA0 + aoff1 + mm * 1024);
  }
#pragma unroll
  for (int nn = 0; nn < 2; ++nn) {
    bfA[nn][0] = *(const bf16x8*)(pB0 + boff0 + nn * 1024);
    bfA[nn][1] = *(const bf16x8*)(pB0 + boff1 + nn * 1024);
  }

  // main loop: tiles 0..13 (7 pairs); tail t=14 (Ah1(15) only), t=15
#pragma unroll 1
  for (int tp = 0; tp < 7; ++tp) {
    const int ku = tp * 128;
    kq<true, true, 4, true>(acc, afA, bfA, pA0, pB0, pA1, pB1,
                            pA1, pA0, pB0,
                            ga + ku + 64, ga + ku + 128, gb + ku + 128,
                            tid, aoff0, aoff1, boff0, boff1);
    kq<true, true, 4, true>(acc, afA, bfA, pA1, pB1, pA0, pB0,
                            pA0, pA1, pB1,
                            ga + ku + 128, ga + ku + 192, gb + ku + 192,
                            tid, aoff0, aoff1, boff0, boff1);
  }
  kq<true, false, 0, true>(acc, afA, bfA, pA0, pB0, pA1, pB1,
                           pA1, pA0, pB0, ga + 960, ga, gb,
                           tid, aoff0, aoff1, boff0, boff1);
  kq<false, false, -1, false>(acc, afA, bfA, pA1, pB1, pA0, pB0,
                              pA0, pA1, pB1, ga, ga, gb,
                              tid, aoff0, aoff1, boff0, boff1);

  // ---- epilogue: route each 16-col subtile to Q (scaled), K, or Vt ----
#pragma unroll
  for (int m = 0; m < 8; ++m) {
    const int rg = row0 + wm * 128 + m * 16 + quad * 4;  // token row, r=0
    const int bb = rg >> 11, t = rg & 2047;
#pragma unroll
    for (int n = 0; n < 4; ++n) {
      const int cg0 = colm + wn * 64 + n * 16;  // 16-aligned, never spans z
      const int z = cg0 >> 10;
      const int c1 = (cg0 & 1023) + l15;
      if (z == 2) {
        // V -> Vt[(b*16+h)*64+d][t], 8B t-contiguous vector store
        ushort4 w;
        w.x = f32_bf16(acc[m][n][0]);
        w.y = f32_bf16(acc[m][n][1]);
        w.z = f32_bf16(acc[m][n][2]);
        w.w = f32_bf16(acc[m][n][3]);
        *(ushort4*)(Vt + ((size_t)(bb * 16 + (c1 >> 6)) * 64 + (c1 & 63)) * 2048 + t) = w;
      } else {
        u16* C = z ? Kb : Qb;
        const float sc = z ? 1.0f : qscale;
#pragma unroll
        for (int r = 0; r < 4; ++r)
          C[(size_t)(rg + r) * 1024 + c1] = f32_bf16(acc[m][n][r] * sc);
      }
    }
  }
}

// ---------------------------------------------------------------------------
// Output-projection GEMM (round-4/7 proven): 128x256, NS=4, read-ahead
// counted-lgkm schedule, 256 blocks = 1 exact round, fp32 out.
// ---------------------------------------------------------------------------
template <int NS, bool SA, bool SB, int VM, bool RD>
__device__ __forceinline__ void kiter(
    f32x4 (&acc)[4][NS], bf16x8 (&afA)[2][2], bf16x8 (&bfAr)[NS / 2][2],
    const u16* __restrict__ aCur, const u16* __restrict__ bCur,
    const u16* __restrict__ aNx, const u16* __restrict__ bNx,
    u16* aStg, u16* bStg,
    const u16* gaN, const u16* gbN2, int tid,
    int aoff0, int aoff1, int boff0, int boff1) {
  constexpr int NB = NS / 2;
  bf16x8 afB[2][2], bfB[NB][2];

  // ---- phase 0 ----
#pragma unroll
  for (int n = 0; n < NB; ++n) {  // bfB first (ph1 waits on it)
    bfB[n][0] = *(const bf16x8*)(bCur + boff0 + (NB + n) * 1024);
    bfB[n][1] = *(const bf16x8*)(bCur + boff1 + (NB + n) * 1024);
  }
#pragma unroll
  for (int m = 0; m < 2; ++m) {
    afB[m][0] = *(const bf16x8*)(aCur + aoff0 + (2 + m) * 1024);
    afB[m][1] = *(const bf16x8*)(aCur + aoff1 + (2 + m) * 1024);
  }
  if (SA) {
    gload_lds16(gaN, aStg + tid * 8);
    gload_lds16(gaN + 65536, aStg + 4096 + tid * 8);
  }
  wait_lgkm<2 * NB + 4>();
  __builtin_amdgcn_s_setprio(1);
#pragma unroll
  for (int m = 0; m < 2; ++m)
#pragma unroll
    for (int n = 0; n < NB; ++n) {
      acc[m][n] = mfma16(afA[m][0], bfAr[n][0], acc[m][n]);
      acc[m][n] = mfma16(afA[m][1], bfAr[n][1], acc[m][n]);
    }
  __builtin_amdgcn_s_setprio(0);
  __builtin_amdgcn_s_barrier();

  // ---- phase 1 ----
  wait_lgkm<4>();
  __builtin_amdgcn_s_setprio(1);
#pragma unroll
  for (int m = 0; m < 2; ++m)
#pragma unroll
    for (int n = 0; n < NB; ++n) {
      acc[m][NB + n] = mfma16(afA[m][0], bfB[n][0], acc[m][NB + n]);
      acc[m][NB + n] = mfma16(afA[m][1], bfB[n][1], acc[m][NB + n]);
    }
  __builtin_amdgcn_s_setprio(0);
  __builtin_amdgcn_s_barrier();

  // ---- phase 2 ----
  if (SB) {
#pragma unroll
    for (int ld = 0; ld < NS; ++ld)
      gload_lds16(gbN2 + ld * 65536, bStg + ld * 4096 + tid * 8);
  }
  if (VM >= 0) wait_vm<(VM >= 0 ? VM : 0)>();
  wait_lgkm<0>();
  __builtin_amdgcn_s_setprio(1);
#pragma unroll
  for (int m = 0; m < 2; ++m)
#pragma unroll
    for (int n = 0; n < NB; ++n) {
      acc[2 + m][n] = mfma16(afB[m][0], bfAr[n][0], acc[2 + m][n]);
      acc[2 + m][n] = mfma16(afB[m][1], bfAr[n][1], acc[2 + m][n]);
    }
  __builtin_amdgcn_s_setprio(0);
  __builtin_amdgcn_s_barrier();

  // ---- phase 3 ----
  if (RD) {
#pragma unroll
    for (int m = 0; m < 2; ++m) {  // afA first, then bfA (ph0 drains both)
      afA[m][0] = *(const bf16x8*)(aNx + aoff0 + m * 1024);
      afA[m][1] = *(const bf16x8*)(aNx + aoff1 + m * 1024);
    }
#pragma unroll
    for (int n = 0; n < NB; ++n) {
      bfAr[n][0] = *(const bf16x8*)(bNx + boff0 + n * 1024);
      bfAr[n][1] = *(const bf16x8*)(bNx + boff1 + n * 1024);
    }
    __builtin_amdgcn_sched_barrier(0);  // reads issued before this MFMA
  }
  __builtin_amdgcn_s_setprio(1);
#pragma unroll
  for (int m = 0; m < 2; ++m)
#pragma unroll
    for (int n = 0; n < NB; ++n) {
      acc[2 + m][NB + n] = mfma16(afB[m][0], bfB[n][0], acc[2 + m][NB + n]);
      acc[2 + m][NB + n] = mfma16(afB[m][1], bfB[n][1], acc[2 + m][NB + n]);
    }
  __builtin_amdgcn_s_setprio(0);
  __builtin_amdgcn_s_barrier();
}

__global__ __launch_bounds__(512, 2) void proj8p(
    const u16* __restrict__ A, const u16* __restrict__ Bc,
    float* __restrict__ Cf) {
  constexpr int NS = 4;
  constexpr int NB = NS / 2;
  constexpr int WN = NS * 16;
  constexpr int K = 1024;
  __shared__ u16 As[2][8192];
  __shared__ u16 Bs[2][NS * 4096];

  const int ord = blockIdx.x;
  const int xcd = ord & 7, g = ord >> 3;
  const int rt = xcd * 8 + (g & 7);
  const int ct = g >> 3;
  const int colm = ct * (NS * 64);
  const int row0 = rt * 128;

  const int tid = threadIdx.x;
  const int lane = tid & 63, wid = tid >> 6;
  const int quad = lane >> 4, l15 = lane & 15;
  const int wm = wid >> 2, wn = wid & 3;

  const int srow = tid >> 3;
  const int selem = ((tid & 7) ^ (srow & 7)) * 8;
  const u16* ga = A + (size_t)(row0 + srow) * K + selem;
  const u16* gb = Bc + (size_t)(colm + srow) * K + selem;

  u16* pA0 = &As[0][0];
  u16* pA1 = &As[1][0];
  u16* pB0 = &Bs[0][0];
  u16* pB1 = &Bs[1][0];

  const int swz = 8 * (quad ^ (l15 & 3));
  const int kof = 32 * ((l15 >> 2) & 1);
  const int aoff0 = (wm * 64 + l15) * 64 + swz + kof;
  const int aoff1 = (wm * 64 + l15) * 64 + swz + (32 - kof);
  const int boff0 = (wn * WN + l15) * 64 + swz + kof;
  const int boff1 = (wn * WN + l15) * 64 + swz + (32 - kof);

  f32x4 acc[4][NS];
  const f32x4 zero = {0.f, 0.f, 0.f, 0.f};
#pragma unroll
  for (int m = 0; m < 4; ++m)
#pragma unroll
    for (int n = 0; n < NS; ++n) acc[m][n] = zero;

  bf16x8 afA[2][2], bfAr[NB][2];

  gload_lds16(ga, pA0 + tid * 8);
  gload_lds16(ga + 65536, pA0 + 4096 + tid * 8);
#pragma unroll
  for (int ld = 0; ld < NS; ++ld)
    gload_lds16(gb + ld * 65536, pB0 + ld * 4096 + tid * 8);
#pragma unroll
  for (int ld = 0; ld < NS; ++ld)
    gload_lds16(gb + 64 + ld * 65536, pB1 + ld * 4096 + tid * 8);
  wait_vm<NS>();
  __builtin_amdgcn_s_barrier();
#pragma unroll
  for (int m = 0; m < 2; ++m) {
    afA[m][0] = *(const bf16x8*)(pA0 + aoff0 + m * 1024);
    afA[m][1] = *(const bf16x8*)(pA0 + aoff1 + m * 1024);
  }
#pragma unroll
  for (int n = 0; n < NB; ++n) {
    bfAr[n][0] = *(const bf16x8*)(pB0 + boff0 + n * 1024);
    bfAr[n][1] = *(const bf16x8*)(pB0 + boff1 + n * 1024);
  }

#pragma unroll 1
  for (int tp = 0; tp < 7; ++tp) {
    const int kb = tp * 128;
    kiter<NS, true, true, NS, true>(acc, afA, bfAr, pA0, pB0, pA1, pB1,
                                    pA1, pB0, ga + kb + 64, gb + kb + 128,
                                    tid, aoff0, aoff1, boff0, boff1);
    kiter<NS, true, true, NS, true>(acc, afA, bfAr, pA1, pB1, pA0, pB0,
                                    pA0, pB1, ga + kb + 128, gb + kb + 192,
                                    tid, aoff0, aoff1, boff0, boff1);
  }
  kiter<NS, true, false, 0, true>(acc, afA, bfAr, pA0, pB0, pA1, pB1,
                                  pA1, pB0, ga + 960, gb, tid,
                                  aoff0, aoff1, boff0, boff1);
  kiter<NS, false, false, -1, false>(acc, afA, bfAr, pA1, pB1, pA0, pB0,
                                     pA0, pB1, ga, gb, tid,
                                     aoff0, aoff1, boff0, boff1);

#pragma unroll
  for (int m = 0; m < 4; ++m) {
    const int rg = row0 + wm * 64 + m * 16 + quad * 4;
#pragma unroll
    for (int n = 0; n < NS; ++n) {
      const int cg = colm + wn * WN + n * 16 + l15;
#pragma unroll
      for (int r = 0; r < 4; ++r)
        Cf[(size_t)(rg + r) * 1024 + cg] = acc[m][n][r];
    }
  }
}

// ---------------------------------------------------------------------------
// Flash attention, causal, KEY-SPLIT blocks (round 7, unchanged).
// 512 threads = 8 waves: waves 0-3 keys [0,n/2), waves 4-7 keys [n/2,n).
// Max-free softmax -> partials additive; in-LDS merge. Longest-first grid.
// ---------------------------------------------------------------------------
__global__ __launch_bounds__(512, 4) void attn_kernel(
    const u16* __restrict__ Qb, const u16* __restrict__ Kb,
    const u16* __restrict__ Vt, u16* __restrict__ Ob, int T) {
  // carve: Ks[2 str][3][2048] | Vs[2 str][3][2048] | Ps[8][1280]  (u16 units)
  __shared__ __align__(16) u16 smem[12288 * 2 + 8 * 1280];

  const int ord = blockIdx.x;
  const int qblk = 15 - (ord >> 6);   // longest first
  const int bh = ord & 63;
  const int b = bh >> 4, h = bh & 15;
  const int tid = threadIdx.x, lane = tid & 63, wid = tid >> 6;  // 0..7
  const int qwave = wid & 3, half = wid >> 2;
  const int quad = lane >> 4, l15 = lane & 15;
  const int qb0 = qblk * 128;
  const int D = 1024;
  const int sw = l15 & 7;          // K-row swizzle key
  const int swv = (l15 >> 1) & 3;  // V-row swizzle key

  const int n = 4 * (qblk + 1);    // total key tiles for this q-tile
  const int nt2 = n >> 1;          // per-stream tiles (>= 2)
  const int tb0 = half * nt2;      // global tile offset of this stream

  u16* KsB = smem + half * 6144;
  u16* VsB = smem + 12288 + half * 6144;
  u16* PsW = smem + 24576 + wid * 1280;

  // Q fragments (B-operand: n=l15 -> q, k=quad*8+j -> feat), 2 q-subtiles
  bf16x8 qf[2][2];
#pragma unroll
  for (int qs = 0; qs < 2; ++qs) {
    const int q = qb0 + qwave * 32 + qs * 16 + l15;
    const u16* qp = Qb + ((size_t)b * T + q) * D + h * 64 + quad * 8;
    qf[qs][0] = *(const bf16x8*)(qp);
    qf[qs][1] = *(const bf16x8*)(qp + 32);
  }

  const f32x4 zero = {0.f, 0.f, 0.f, 0.f};
  f32x4 o[2][4];  // [q-subtile][d-subtile]
#pragma unroll
  for (int ms = 0; ms < 2; ++ms)
    for (int nt = 0; nt < 4; ++nt) o[ms][nt] = zero;
  float l_acc[2] = {0.f, 0.f};

  bf16x8 vf_h[4];
  bf16x8 pf_h[2];

  // staging source addresses (group-local tid, per-stream key base)
  const int t256 = tid & 255;
  const int krow = t256 >> 3, kslot = t256 & 7;
  const u16* kg = Kb + ((size_t)b * T + tb0 * 32 + krow) * D + h * 64 +
                  (kslot ^ (krow & 7)) * 8;
  const int vrow = t256 >> 2, vslot = t256 & 3;
  const u16* vg = Vt + ((size_t)bh * 64 + vrow) * T + tb0 * 32 +
                  (vslot ^ ((vrow >> 1) & 3)) * 8;

  // prefetch tiles 0 and 1 of this stream
  gload_lds16(kg, KsB + t256 * 8);
  gload_lds16(vg, VsB + t256 * 8);
  gload_lds16(kg + (size_t)32 * D, KsB + 2048 + t256 * 8);
  gload_lds16(vg + 32, VsB + 2048 + t256 * 8);
  barrier_vm2();  // tile-0 data landed; tile-1 loads may stay in flight

  int c = 0;  // ring index t % 3
  for (int t = 0; t < nt2; ++t) {
    // prefetch tile t+2 (clamped dummy at the tail keeps vmcnt uniform)
    {
      int pb = c + 2; if (pb >= 3) pb -= 3;
      const int tp = (t + 2 < nt2) ? t + 2 : nt2 - 1;
      const size_t kv = (size_t)tp * 32;
      gload_lds16(kg + kv * D, KsB + pb * 2048 + t256 * 8);
      gload_lds16(vg + kv, VsB + pb * 2048 + t256 * 8);
    }
    const u16* KsC = KsB + c * 2048;
    const u16* VsC = VsB + c * 2048;
    const int gt = tb0 + t;          // global key-tile index
    const int kv0 = gt * 32;

    // --- QK(t): S^T[key][q], A = K rows (2 subtiles), B = Q (2 subtiles)
    f32x4 s[2][2];
    __builtin_amdgcn_s_setprio(1);
#pragma unroll
    for (int st = 0; st < 2; ++st) {
      const int row = st * 16 + l15;
      const bf16x8 k0 = *(const bf16x8*)(&KsC[row * 64 + ((quad ^ sw) * 8)]);
      const bf16x8 k1 = *(const bf16x8*)(&KsC[row * 64 + (((4 + quad) ^ sw) * 8)]);
#pragma unroll
      for (int qs = 0; qs < 2; ++qs) {
        s[st][qs] = mfma16(k0, qf[qs][0], zero);
        s[st][qs] = mfma16(k1, qf[qs][1], s[st][qs]);
      }
    }

    // --- PV(t-1): independent of s(t); overlaps QK in the MFMA pipe
    if (t > 0) {
#pragma unroll
      for (int nt = 0; nt < 4; ++nt)
#pragma unroll
        for (int ms = 0; ms < 2; ++ms)
          o[ms][nt] = mfma16(pf_h[ms], vf_h[nt], o[ms][nt]);
    }
    __builtin_amdgcn_s_setprio(0);

    // --- V(t) fragments into registers (independent of s)
#pragma unroll
    for (int nt = 0; nt < 4; ++nt)
      vf_h[nt] = *(const bf16x8*)(
          &VsC[(nt * 16 + l15) * 32 + ((quad ^ swv) * 8)]);

    // --- causal mask: global tile gt >= n-4 straddles the q-range
    if (gt >= n - 4) {
#pragma unroll
      for (int qs = 0; qs < 2; ++qs) {
        const int q = qb0 + qwave * 32 + qs * 16 + l15;
#pragma unroll
        for (int st = 0; st < 2; ++st)
#pragma unroll
          for (int r = 0; r < 4; ++r) {
            const int key = kv0 + st * 16 + quad * 4 + r;
            if (key > q) s[st][qs][r] = -INFINITY;
          }
      }
    }

    // --- max-free softmax: p = 2^s (Q pre-scaled by log2e); l per-lane
#pragma unroll
    for (int qs = 0; qs < 2; ++qs) {
      float sum = l_acc[qs];
#pragma unroll
      for (int st = 0; st < 2; ++st)
#pragma unroll
        for (int r = 0; r < 4; ++r) {
          const float p = __builtin_amdgcn_exp2f(s[st][qs][r]);
          s[st][qs][r] = p;
          sum += p;
        }
      l_acc[qs] = sum;
    }

    // --- P^T -> LDS (A-layout for PV), 8B vector stores, stride 40
#pragma unroll
    for (int qs = 0; qs < 2; ++qs)
#pragma unroll
      for (int st = 0; st < 2; ++st) {
        bf16x4 w;
        w[0] = (__bf16)s[st][qs][0];
        w[1] = (__bf16)s[st][qs][1];
        w[2] = (__bf16)s[st][qs][2];
        w[3] = (__bf16)s[st][qs][3];
        *(bf16x4*)(&PsW[(qs * 16 + l15) * 40 + st * 16 + quad * 4]) = w;
      }

    // --- P(t) fragments for next iteration's PV (same-wave DS is in-order)
#pragma unroll
    for (int ms = 0; ms < 2; ++ms)
      pf_h[ms] = *(const bf16x8*)(&PsW[(ms * 16 + l15) * 40 + quad * 8]);

    barrier_vm2();  // t+1 data landed; t+2 loads stay in flight
    ++c; if (c >= 3) c = 0;
  }

  // --- flush PV(last)
  __builtin_amdgcn_s_setprio(1);
#pragma unroll
  for (int nt = 0; nt < 4; ++nt)
#pragma unroll
    for (int ms = 0; ms < 2; ++ms)
      o[ms][nt] = mfma16(pf_h[ms], vf_h[nt], o[ms][nt]);
  __builtin_amdgcn_s_setprio(0);

  // --- merge halves via LDS (overlaid on K/V rings; drain async loads 1st)
  wait_vm<0>();
  __syncthreads();
  float* mo = (float*)smem;            // [4][64][32] f32 (32 KB)
  float* ml = (float*)smem + 8192;     // [4][64][2]  f32 (2 KB)
  if (half == 1) {
    float* dst = mo + (qwave * 64 + lane) * 32;
#pragma unroll
    for (int ms = 0; ms < 2; ++ms)
#pragma unroll
      for (int nt = 0; nt < 4; ++nt)
#pragma unroll
        for (int r = 0; r < 4; ++r)
          dst[ms * 16 + nt * 4 + r] = o[ms][nt][r];
    ml[(qwave * 64 + lane) * 2 + 0] = l_acc[0];
    ml[(qwave * 64 + lane) * 2 + 1] = l_acc[1];
  }
  __syncthreads();
  if (half == 1) return;
  {
    const float* src = mo + (qwave * 64 + lane) * 32;
#pragma unroll
    for (int ms = 0; ms < 2; ++ms)
#pragma unroll
      for (int nt = 0; nt < 4; ++nt)
#pragma unroll
        for (int r = 0; r < 4; ++r)
          o[ms][nt][r] += src[ms * 16 + nt * 4 + r];
    l_acc[0] += ml[(qwave * 64 + lane) * 2 + 0];
    l_acc[1] += ml[(qwave * 64 + lane) * 2 + 1];
  }

  // epilogue: reduce l across the 4 quads (once), normalize, store
#pragma unroll
  for (int ms = 0; ms < 2; ++ms) {
    float sum = l_acc[ms];
    sum += __shfl_xor(sum, 16);
    sum += __shfl_xor(sum, 32);
    const float linv = 1.0f / sum;
    float lr[4];
#pragma unroll
    for (int r = 0; r < 4; ++r) lr[r] = __shfl(linv, quad * 4 + r);
#pragma unroll
    for (int r = 0; r < 4; ++r) {
      const int qo = qb0 + qwave * 32 + ms * 16 + quad * 4 + r;
      u16* op = Ob + ((size_t)b * T + qo) * D + h * 64 + l15;
#pragma unroll
      for (int nt = 0; nt < 4; ++nt)
        op[nt * 16] = f32_bf16(o[ms][nt][r] * lr[r]);
    }
  }
}

// ---------------------------------------------------------------------------
extern "C" void kernel_launch(void* const* d_in, const int* in_sizes, int n_in,
                              void* d_out, int out_size, void* d_ws, size_t ws_size,
                              hipStream_t stream) {
  const float* x  = (const float*)d_in[0];
  const float* wq = (const float*)d_in[1];
  const float* wk = (const float*)d_in[2];
  const float* wv = (const float*)d_in[3];
  const float* wo = (const float*)d_in[4];

  const int B = 4, T = 2048, D = 1024;
  const int M = B * T;  // 8192

  u16* ws = (u16*)d_ws;
  u16* xb  = ws;                         // M*D
  u16* wqb = xb  + (size_t)M * D;        // D*D (contiguous with xb: fused cast;
  u16* wkb = wqb + (size_t)D * D;        //  wq/wk/wv contiguous -> one 3072x1024 B)
  u16* wvb = wkb + (size_t)D * D;
  u16* wob = wvb + (size_t)D * D;
  u16* Qb  = wob + (size_t)D * D;        // M*D (pre-scaled by log2e/8)
  u16* Kb  = Qb  + (size_t)M * D;
  u16* Vt  = Kb  + (size_t)M * D;        // transposed V: [bh][d][t] (from GEMM)
  u16* Ob  = Vt  + (size_t)M * D;        // attention output

  (void)wkb; (void)wvb;

  // fused cast (dst regions xb..wob are contiguous)
  const int n_x = M * D / 4, n_w = D * D / 4;
  const int n_tot = n_x + 4 * n_w;
  cvt_all_kernel<<<(n_tot + 255) / 256, 256, 0, stream>>>(x, wq, wk, wv, wo,
                                                          xb, n_x, n_w);

  // fused QKV projection: 32 row-tiles x 12 col-tiles (256x256) = 384 blocks
  // Q scaled by (1/sqrt(Dh)) * log2(e)
  qkv256<<<384, 512, 0, stream>>>(
      xb, wqb, Qb, Kb, Vt, 0.125f * 1.44269504f);

  // flash attention: 16 q-tiles x 64 bh = 1024 blocks of 512 threads,
  // key-split halves in-block, longest blocks dispatched first
  attn_kernel<<<dim3(1024), 512, 0, stream>>>(Qb, Kb, Vt, Ob, T);

  // output projection -> fp32 d_out: 64 x 4 (128x256) = 256 blocks (1 round)
  proj8p<<<256, 512, 0, stream>>>(Ob, wob, (float*)d_out);
}

// Round 9
// 222.849 us; speedup vs baseline: 1.0774x; 1.0774x over previous
//
#include <hip/hip_runtime.h>
#include <cstdint>
#include <math.h>

// ---------------------------------------------------------------------------
// CausalSelfAttention (B=4, T=2048, D=1024, H=16, Dh=64), fp32 in/out,
// bf16 MFMA compute internally.
// Pipeline: fused cast -> fused QKV GEMM (128x384, read-ahead counted-lgkm,
//           round-7 config MINUS 2 redundant barriers/K-tile) -> flash
//           attention (key-split + setprio, round 7) -> output projection
//           (128x256, same 2-barrier schedule).
//
// Round-9 rationale: round 8's 256^2 tile regressed purely from grid
// quantization (384 blocks = 1.5 rounds at 1 block/CU). Round-7 QKV wall
// is 4950 cyc/K-tile vs 1536 matrix + ~740 LDS -> barrier-convoy-bound
// (4 block barriers/tile, 8 waves). Only 2 barriers are semantically
// required: ph1-end (B(t) reads complete before B(t+2) stage issues) and
// ph2-end (vmcnt globalized before ph3 cross-buffer read-ahead). ph0-end
// and ph3-end barriers removed; all overwrite/read orderings re-derived
// against the retained barriers (per-wave lgkm ledgers unchanged).
// ---------------------------------------------------------------------------

typedef unsigned short u16;
typedef __bf16 bf16x8 __attribute__((ext_vector_type(8)));
typedef __bf16 bf16x4 __attribute__((ext_vector_type(4)));
typedef float f32x4 __attribute__((ext_vector_type(4)));

__device__ __forceinline__ u16 f32_bf16(float f) {  // round-nearest-even
  union { float f; uint32_t u; } c; c.f = f;
  uint32_t u = c.u;
  return (u16)((u + 0x7FFFu + ((u >> 16) & 1u)) >> 16);
}

__device__ __forceinline__ f32x4 mfma16(bf16x8 a, bf16x8 b, f32x4 c) {
  return __builtin_amdgcn_mfma_f32_16x16x32_bf16(a, b, c, 0, 0, 0);
}

// async global->LDS, 16B/lane. LDS dest must be wave-uniform base + lane*16.
__device__ __forceinline__ void gload_lds16(const u16* g, u16* l) {
  __builtin_amdgcn_global_load_lds(
      (const __attribute__((address_space(1))) void*)g,
      (__attribute__((address_space(3))) void*)l, 16, 0, 0);
}

template <int N>
__device__ __forceinline__ void wait_lgkm() {
  if (N == 0)       asm volatile("s_waitcnt lgkmcnt(0)" ::: "memory");
  else if (N == 4)  asm volatile("s_waitcnt lgkmcnt(4)" ::: "memory");
  else if (N == 8)  asm volatile("s_waitcnt lgkmcnt(8)" ::: "memory");
  else if (N == 10) asm volatile("s_waitcnt lgkmcnt(10)" ::: "memory");
  __builtin_amdgcn_sched_barrier(0);
}
template <int N>
__device__ __forceinline__ void wait_vm() {
  if (N == 6)      asm volatile("s_waitcnt vmcnt(6)" ::: "memory");
  else if (N == 4) asm volatile("s_waitcnt vmcnt(4)" ::: "memory");
  else if (N == 2) asm volatile("s_waitcnt vmcnt(2)" ::: "memory");
  else if (N == 0) asm volatile("s_waitcnt vmcnt(0)" ::: "memory");
  __builtin_amdgcn_sched_barrier(0);
}

// barrier that does NOT drain the newest 2 vm loads (attn t+2 prefetch)
__device__ __forceinline__ void barrier_vm2() {
  asm volatile("s_waitcnt vmcnt(2)" ::: "memory");
  __builtin_amdgcn_sched_barrier(0);
  __builtin_amdgcn_s_barrier();
}

// ---------------------------------------------------------------------------
// fused cast fp32->bf16 of x + 4 weights into contiguous ws region
// ---------------------------------------------------------------------------
__global__ __launch_bounds__(256) void cvt_all_kernel(
    const float* __restrict__ x,
    const float* __restrict__ wq, const float* __restrict__ wk,
    const float* __restrict__ wv, const float* __restrict__ wo,
    u16* __restrict__ dst, int n_x, int n_w) {
  int i = blockIdx.x * 256 + threadIdx.x;
  const float* src;
  int off;
  if (i < n_x) { src = x; off = i; }
  else {
    int j = i - n_x;
    int w = j / n_w;  off = j - w * n_w;
    src = (w == 0) ? wq : (w == 1) ? wk : (w == 2) ? wv : wo;
  }
  float4 f = ((const float4*)src)[off];
  ushort4 o;
  o.x = f32_bf16(f.x); o.y = f32_bf16(f.y);
  o.z = f32_bf16(f.z); o.w = f32_bf16(f.w);
  ((ushort4*)dst)[i] = o;
}

// ---------------------------------------------------------------------------
// Read-ahead GEMM (round-7 config, 2 barriers/tile): C = A * B^T.
// BM=128, BN=NS*64 (QKV: NS=6 -> 384, proj: NS=4 -> 256), BK=64,
// 512 threads = 8 waves (2M x 4N), per-wave 64 x NS*16.
//
// Ordering proof for the 2 retained barriers:
//  ph1-end BAR: every wave's bfB (B(t) cols, issued ph0) drained by its
//    lgkm(4)@ph1, and B(t) read-ahead (bfA, issued ph3(t-1)) drained by its
//    lgkm(10)@ph0 -> ALL B(t) reads complete chip-wide => ph2's B(t+2)
//    stage may overwrite. A(t)'s afB reads drain at lgkm(0)@ph2, before...
//  ph2-end BAR: globalizes both vmcnt(NS) (tile t+1 fully landed -> ph3's
//    cross-buffer read-ahead safe) and lgkm(0) (A(t) reads complete ->
//    ph0(t+1)'s A(t+2) stage may overwrite A(t)).
//  ph0-end / ph3-end barriers protect nothing -> removed.
// ---------------------------------------------------------------------------
template <int NS, bool SA, bool SB, int VM, bool RD>
__device__ __forceinline__ void kiter(
    f32x4 (&acc)[4][NS], bf16x8 (&afA)[2][2], bf16x8 (&bfAr)[NS / 2][2],
    const u16* __restrict__ aCur, const u16* __restrict__ bCur,
    const u16* __restrict__ aNx, const u16* __restrict__ bNx,
    u16* aStg, u16* bStg,
    const u16* gaN, const u16* gbN2, int tid,
    int aoff0, int aoff1, int boff0, int boff1) {
  constexpr int NB = NS / 2;
  bf16x8 afB[2][2], bfB[NB][2];

  // ---- phase 0 ----
#pragma unroll
  for (int n = 0; n < NB; ++n) {  // bfB first (ph1 waits on it)
    bfB[n][0] = *(const bf16x8*)(bCur + boff0 + (NB + n) * 1024);
    bfB[n][1] = *(const bf16x8*)(bCur + boff1 + (NB + n) * 1024);
  }
#pragma unroll
  for (int m = 0; m < 2; ++m) {
    afB[m][0] = *(const bf16x8*)(aCur + aoff0 + (2 + m) * 1024);
    afB[m][1] = *(const bf16x8*)(aCur + aoff1 + (2 + m) * 1024);
  }
  if (SA) {
    gload_lds16(gaN, aStg + tid * 8);
    gload_lds16(gaN + 65536, aStg + 4096 + tid * 8);
  }
  wait_lgkm<2 * NB + 4>();
  __builtin_amdgcn_s_setprio(1);
#pragma unroll
  for (int m = 0; m < 2; ++m)
#pragma unroll
    for (int n = 0; n < NB; ++n) {
      acc[m][n] = mfma16(afA[m][0], bfAr[n][0], acc[m][n]);
      acc[m][n] = mfma16(afA[m][1], bfAr[n][1], acc[m][n]);
    }
  __builtin_amdgcn_s_setprio(0);
  // (no barrier: ph1 issues no LDS writes; per-wave order suffices)

  // ---- phase 1 ----
  wait_lgkm<4>();
  __builtin_amdgcn_s_setprio(1);
#pragma unroll
  for (int m = 0; m < 2; ++m)
#pragma unroll
    for (int n = 0; n < NB; ++n) {
      acc[m][NB + n] = mfma16(afA[m][0], bfB[n][0], acc[m][NB + n]);
      acc[m][NB + n] = mfma16(afA[m][1], bfB[n][1], acc[m][NB + n]);
    }
  __builtin_amdgcn_s_setprio(0);
  __builtin_amdgcn_s_barrier();  // B(t) reads complete chip-wide

  // ---- phase 2 ----
  if (SB) {
#pragma unroll
    for (int ld = 0; ld < NS; ++ld)
      gload_lds16(gbN2 + ld * 65536, bStg + ld * 4096 + tid * 8);
  }
  if (VM >= 0) wait_vm<(VM >= 0 ? VM : 0)>();
  wait_lgkm<0>();
  __builtin_amdgcn_s_setprio(1);
#pragma unroll
  for (int m = 0; m < 2; ++m)
#pragma unroll
    for (int n = 0; n < NB; ++n) {
      acc[2 + m][n] = mfma16(afB[m][0], bfAr[n][0], acc[2 + m][n]);
      acc[2 + m][n] = mfma16(afB[m][1], bfAr[n][1], acc[2 + m][n]);
    }
  __builtin_amdgcn_s_setprio(0);
  __builtin_amdgcn_s_barrier();  // globalizes vmcnt + A(t)-reads-complete

  // ---- phase 3 ----
  if (RD) {
#pragma unroll
    for (int m = 0; m < 2; ++m) {  // afA first, then bfA (ph0 drains both)
      afA[m][0] = *(const bf16x8*)(aNx + aoff0 + m * 1024);
      afA[m][1] = *(const bf16x8*)(aNx + aoff1 + m * 1024);
    }
#pragma unroll
    for (int n = 0; n < NB; ++n) {
      bfAr[n][0] = *(const bf16x8*)(bNx + boff0 + n * 1024);
      bfAr[n][1] = *(const bf16x8*)(bNx + boff1 + n * 1024);
    }
    __builtin_amdgcn_sched_barrier(0);  // reads issued before this MFMA
  }
  __builtin_amdgcn_s_setprio(1);
#pragma unroll
  for (int m = 0; m < 2; ++m)
#pragma unroll
    for (int n = 0; n < NB; ++n) {
      acc[2 + m][NB + n] = mfma16(afB[m][0], bfB[n][0], acc[2 + m][NB + n]);
      acc[2 + m][NB + n] = mfma16(afB[m][1], bfB[n][1], acc[2 + m][NB + n]);
    }
  __builtin_amdgcn_s_setprio(0);
  // (no barrier: next ph0's reads are vmcnt-proven; its stage overwrites
  //  A(t-1) whose reads were globalized at ph2-end)
}

template <int MODE>  // 0 = QKV (NS=6, routes cols to Q/K/Vt), 1 = proj (NS=4, fp32)
__global__ __launch_bounds__(512, 2) void gemm8p(
    const u16* __restrict__ A, const u16* __restrict__ Bc,
    u16* __restrict__ Qb, u16* __restrict__ Kb, u16* __restrict__ Vt,
    float* __restrict__ Cf, float qscale) {
  constexpr int NS = (MODE == 0) ? 6 : 4;   // n-subtiles per wave
  constexpr int NB = NS / 2;
  constexpr int WN = NS * 16;               // per-wave N (96 / 64)
  constexpr int K = 1024;
  __shared__ u16 As[2][8192];               // [dbuf][128 rows x 64 k]
  __shared__ u16 Bs[2][NS * 4096];          // [dbuf][NS*64 rows x 64 k]

  // XCD-bijective decode: per XCD 8 row-strips x (8 or 4) col-tiles
  const int ord = blockIdx.x;
  const int xcd = ord & 7, g = ord >> 3;
  const int rt = xcd * 8 + (g & 7);         // [0,64)
  const int ct = g >> 3;                    // MODE0: [0,8), MODE1: [0,4)
  const int colm = ct * (NS * 64);
  const int row0 = rt * 128;

  const int tid = threadIdx.x;
  const int lane = tid & 63, wid = tid >> 6;
  const int quad = lane >> 4, l15 = lane & 15;
  const int wm = wid >> 2, wn = wid & 3;

  // staging: linear LDS dest, pre-swizzled global source
  const int srow = tid >> 3;
  const int selem = ((tid & 7) ^ (srow & 7)) * 8;
  const u16* ga = A + (size_t)(row0 + srow) * K + selem;
  const u16* gb = Bc + (size_t)(colm + srow) * K + selem;

  u16* pA0 = &As[0][0];
  u16* pA1 = &As[1][0];
  u16* pB0 = &Bs[0][0];
  u16* pB1 = &Bs[1][0];

  // swizzled fragment read offsets (elements); row-local swizzle unchanged
  const int swz = 8 * (quad ^ (l15 & 3));
  const int kof = 32 * ((l15 >> 2) & 1);
  const int aoff0 = (wm * 64 + l15) * 64 + swz + kof;
  const int aoff1 = (wm * 64 + l15) * 64 + swz + (32 - kof);
  const int boff0 = (wn * WN + l15) * 64 + swz + kof;
  const int boff1 = (wn * WN + l15) * 64 + swz + (32 - kof);

  f32x4 acc[4][NS];
  const f32x4 zero = {0.f, 0.f, 0.f, 0.f};
#pragma unroll
  for (int m = 0; m < 4; ++m)
#pragma unroll
    for (int n = 0; n < NS; ++n) acc[m][n] = zero;

  bf16x8 afA[2][2], bfAr[NB][2];

  // prologue: stage A(0), B(0), B(1); vmcnt(NS) leaves B(1) in flight;
  // then pre-issue tile-0 ph0 fragments (afA, bfA)
  gload_lds16(ga, pA0 + tid * 8);
  gload_lds16(ga + 65536, pA0 + 4096 + tid * 8);
#pragma unroll
  for (int ld = 0; ld < NS; ++ld)
    gload_lds16(gb + ld * 65536, pB0 + ld * 4096 + tid * 8);
#pragma unroll
  for (int ld = 0; ld < NS; ++ld)
    gload_lds16(gb + 64 + ld * 65536, pB1 + ld * 4096 + tid * 8);
  wait_vm<NS>();
  __builtin_amdgcn_s_barrier();
#pragma unroll
  for (int m = 0; m < 2; ++m) {
    afA[m][0] = *(const bf16x8*)(pA0 + aoff0 + m * 1024);
    afA[m][1] = *(const bf16x8*)(pA0 + aoff1 + m * 1024);
  }
#pragma unroll
  for (int n = 0; n < NB; ++n) {
    bfAr[n][0] = *(const bf16x8*)(pB0 + boff0 + n * 1024);
    bfAr[n][1] = *(const bf16x8*)(pB0 + boff1 + n * 1024);
  }

  // main loop: t=0..13 (7 pairs); tail t=14 (stage A(15), vmcnt 0), t=15
#pragma unroll 1
  for (int tp = 0; tp < 7; ++tp) {
    const int kb = tp * 128;
    kiter<NS, true, true, NS, true>(acc, afA, bfAr, pA0, pB0, pA1, pB1,
                                    pA1, pB0, ga + kb + 64, gb + kb + 128,
                                    tid, aoff0, aoff1, boff0, boff1);
    kiter<NS, true, true, NS, true>(acc, afA, bfAr, pA1, pB1, pA0, pB0,
                                    pA0, pB1, ga + kb + 128, gb + kb + 192,
                                    tid, aoff0, aoff1, boff0, boff1);
  }
  kiter<NS, true, false, 0, true>(acc, afA, bfAr, pA0, pB0, pA1, pB1,
                                  pA1, pB0, ga + 960, gb,
                                  tid, aoff0, aoff1, boff0, boff1);
  kiter<NS, false, false, -1, false>(acc, afA, bfAr, pA1, pB1, pA0, pB0,
                                     pA0, pB1, ga, gb,
                                     tid, aoff0, aoff1, boff0, boff1);

  // ---- epilogue ----
  if (MODE == 1) {
#pragma unroll
    for (int m = 0; m < 4; ++m) {
      const int rg = row0 + wm * 64 + m * 16 + quad * 4;
#pragma unroll
      for (int n = 0; n < NS; ++n) {
        const int cg = colm + wn * WN + n * 16 + l15;
#pragma unroll
        for (int r = 0; r < 4; ++r)
          Cf[(size_t)(rg + r) * 1024 + cg] = acc[m][n][r];
      }
    }
    return;
  }
  // MODE 0: route each 16-col subtile to Q (scaled), K, or Vt (transposed)
#pragma unroll
  for (int m = 0; m < 4; ++m) {
    const int rg = row0 + wm * 64 + m * 16 + quad * 4;  // token row, r=0
    const int bb = rg >> 11, t = rg & 2047;
#pragma unroll
    for (int n = 0; n < NS; ++n) {
      const int cg0 = colm + wn * WN + n * 16;  // 16-aligned, never spans z
      const int z = cg0 >> 10;
      const int c1 = (cg0 & 1023) + l15;
      if (z == 2) {
        // V -> Vt[(b*16+h)*64+d][t], 8B t-contiguous vector store
        ushort4 w;
        w.x = f32_bf16(acc[m][n][0]);
        w.y = f32_bf16(acc[m][n][1]);
        w.z = f32_bf16(acc[m][n][2]);
        w.w = f32_bf16(acc[m][n][3]);
        *(ushort4*)(Vt + ((size_t)(bb * 16 + (c1 >> 6)) * 64 + (c1 & 63)) * 2048 + t) = w;
      } else {
        u16* C = z ? Kb : Qb;
        const float sc = z ? 1.0f : qscale;
#pragma unroll
        for (int r = 0; r < 4; ++r)
          C[(size_t)(rg + r) * 1024 + c1] = f32_bf16(acc[m][n][r] * sc);
      }
    }
  }
}

// ---------------------------------------------------------------------------
// Flash attention, causal, KEY-SPLIT blocks (round 7, unchanged).
// 512 threads = 8 waves: waves 0-3 keys [0,n/2), waves 4-7 keys [n/2,n).
// Max-free softmax -> partials additive; in-LDS merge. Longest-first grid.
// ---------------------------------------------------------------------------
__global__ __launch_bounds__(512, 4) void attn_kernel(
    const u16* __restrict__ Qb, const u16* __restrict__ Kb,
    const u16* __restrict__ Vt, u16* __restrict__ Ob, int T) {
  // carve: Ks[2 str][3][2048] | Vs[2 str][3][2048] | Ps[8][1280]  (u16 units)
  __shared__ __align__(16) u16 smem[12288 * 2 + 8 * 1280];

  const int ord = blockIdx.x;
  const int qblk = 15 - (ord >> 6);   // longest first
  const int bh = ord & 63;
  const int b = bh >> 4, h = bh & 15;
  const int tid = threadIdx.x, lane = tid & 63, wid = tid >> 6;  // 0..7
  const int qwave = wid & 3, half = wid >> 2;
  const int quad = lane >> 4, l15 = lane & 15;
  const int qb0 = qblk * 128;
  const int D = 1024;
  const int sw = l15 & 7;          // K-row swizzle key
  const int swv = (l15 >> 1) & 3;  // V-row swizzle key

  const int n = 4 * (qblk + 1);    // total key tiles for this q-tile
  const int nt2 = n >> 1;          // per-stream tiles (>= 2)
  const int tb0 = half * nt2;      // global tile offset of this stream

  u16* KsB = smem + half * 6144;
  u16* VsB = smem + 12288 + half * 6144;
  u16* PsW = smem + 24576 + wid * 1280;

  // Q fragments (B-operand: n=l15 -> q, k=quad*8+j -> feat), 2 q-subtiles
  bf16x8 qf[2][2];
#pragma unroll
  for (int qs = 0; qs < 2; ++qs) {
    const int q = qb0 + qwave * 32 + qs * 16 + l15;
    const u16* qp = Qb + ((size_t)b * T + q) * D + h * 64 + quad * 8;
    qf[qs][0] = *(const bf16x8*)(qp);
    qf[qs][1] = *(const bf16x8*)(qp + 32);
  }

  const f32x4 zero = {0.f, 0.f, 0.f, 0.f};
  f32x4 o[2][4];  // [q-subtile][d-subtile]
#pragma unroll
  for (int ms = 0; ms < 2; ++ms)
    for (int nt = 0; nt < 4; ++nt) o[ms][nt] = zero;
  float l_acc[2] = {0.f, 0.f};

  bf16x8 vf_h[4];
  bf16x8 pf_h[2];

  // staging source addresses (group-local tid, per-stream key base)
  const int t256 = tid & 255;
  const int krow = t256 >> 3, kslot = t256 & 7;
  const u16* kg = Kb + ((size_t)b * T + tb0 * 32 + krow) * D + h * 64 +
                  (kslot ^ (krow & 7)) * 8;
  const int vrow = t256 >> 2, vslot = t256 & 3;
  const u16* vg = Vt + ((size_t)bh * 64 + vrow) * T + tb0 * 32 +
                  (vslot ^ ((vrow >> 1) & 3)) * 8;

  // prefetch tiles 0 and 1 of this stream
  gload_lds16(kg, KsB + t256 * 8);
  gload_lds16(vg, VsB + t256 * 8);
  gload_lds16(kg + (size_t)32 * D, KsB + 2048 + t256 * 8);
  gload_lds16(vg + 32, VsB + 2048 + t256 * 8);
  barrier_vm2();  // tile-0 data landed; tile-1 loads may stay in flight

  int c = 0;  // ring index t % 3
  for (int t = 0; t < nt2; ++t) {
    // prefetch tile t+2 (clamped dummy at the tail keeps vmcnt uniform)
    {
      int pb = c + 2; if (pb >= 3) pb -= 3;
      const int tp = (t + 2 < nt2) ? t + 2 : nt2 - 1;
      const size_t kv = (size_t)tp * 32;
      gload_lds16(kg + kv * D, KsB + pb * 2048 + t256 * 8);
      gload_lds16(vg + kv, VsB + pb * 2048 + t256 * 8);
    }
    const u16* KsC = KsB + c * 2048;
    const u16* VsC = VsB + c * 2048;
    const int gt = tb0 + t;          // global key-tile index
    const int kv0 = gt * 32;

    // --- QK(t): S^T[key][q], A = K rows (2 subtiles), B = Q (2 subtiles)
    f32x4 s[2][2];
    __builtin_amdgcn_s_setprio(1);
#pragma unroll
    for (int st = 0; st < 2; ++st) {
      const int row = st * 16 + l15;
      const bf16x8 k0 = *(const bf16x8*)(&KsC[row * 64 + ((quad ^ sw) * 8)]);
      const bf16x8 k1 = *(const bf16x8*)(&KsC[row * 64 + (((4 + quad) ^ sw) * 8)]);
#pragma unroll
      for (int qs = 0; qs < 2; ++qs) {
        s[st][qs] = mfma16(k0, qf[qs][0], zero);
        s[st][qs] = mfma16(k1, qf[qs][1], s[st][qs]);
      }
    }

    // --- PV(t-1): independent of s(t); overlaps QK in the MFMA pipe
    if (t > 0) {
#pragma unroll
      for (int nt = 0; nt < 4; ++nt)
#pragma unroll
        for (int ms = 0; ms < 2; ++ms)
          o[ms][nt] = mfma16(pf_h[ms], vf_h[nt], o[ms][nt]);
    }
    __builtin_amdgcn_s_setprio(0);

    // --- V(t) fragments into registers (independent of s)
#pragma unroll
    for (int nt = 0; nt < 4; ++nt)
      vf_h[nt] = *(const bf16x8*)(
          &VsC[(nt * 16 + l15) * 32 + ((quad ^ swv) * 8)]);

    // --- causal mask: global tile gt >= n-4 straddles the q-range
    if (gt >= n - 4) {
#pragma unroll
      for (int qs = 0; qs < 2; ++qs) {
        const int q = qb0 + qwave * 32 + qs * 16 + l15;
#pragma unroll
        for (int st = 0; st < 2; ++st)
#pragma unroll
          for (int r = 0; r < 4; ++r) {
            const int key = kv0 + st * 16 + quad * 4 + r;
            if (key > q) s[st][qs][r] = -INFINITY;
          }
      }
    }

    // --- max-free softmax: p = 2^s (Q pre-scaled by log2e); l per-lane
#pragma unroll
    for (int qs = 0; qs < 2; ++qs) {
      float sum = l_acc[qs];
#pragma unroll
      for (int st = 0; st < 2; ++st)
#pragma unroll
        for (int r = 0; r < 4; ++r) {
          const float p = __builtin_amdgcn_exp2f(s[st][qs][r]);
          s[st][qs][r] = p;
          sum += p;
        }
      l_acc[qs] = sum;
    }

    // --- P^T -> LDS (A-layout for PV), 8B vector stores, stride 40
#pragma unroll
    for (int qs = 0; qs < 2; ++qs)
#pragma unroll
      for (int st = 0; st < 2; ++st) {
        bf16x4 w;
        w[0] = (__bf16)s[st][qs][0];
        w[1] = (__bf16)s[st][qs][1];
        w[2] = (__bf16)s[st][qs][2];
        w[3] = (__bf16)s[st][qs][3];
        *(bf16x4*)(&PsW[(qs * 16 + l15) * 40 + st * 16 + quad * 4]) = w;
      }

    // --- P(t) fragments for next iteration's PV (same-wave DS is in-order)
#pragma unroll
    for (int ms = 0; ms < 2; ++ms)
      pf_h[ms] = *(const bf16x8*)(&PsW[(ms * 16 + l15) * 40 + quad * 8]);

    barrier_vm2();  // t+1 data landed; t+2 loads stay in flight
    ++c; if (c >= 3) c = 0;
  }

  // --- flush PV(last)
  __builtin_amdgcn_s_setprio(1);
#pragma unroll
  for (int nt = 0; nt < 4; ++nt)
#pragma unroll
    for (int ms = 0; ms < 2; ++ms)
      o[ms][nt] = mfma16(pf_h[ms], vf_h[nt], o[ms][nt]);
  __builtin_amdgcn_s_setprio(0);

  // --- merge halves via LDS (overlaid on K/V rings; drain async loads 1st)
  wait_vm<0>();
  __syncthreads();
  float* mo = (float*)smem;            // [4][64][32] f32 (32 KB)
  float* ml = (float*)smem + 8192;     // [4][64][2]  f32 (2 KB)
  if (half == 1) {
    float* dst = mo + (qwave * 64 + lane) * 32;
#pragma unroll
    for (int ms = 0; ms < 2; ++ms)
#pragma unroll
      for (int nt = 0; nt < 4; ++nt)
#pragma unroll
        for (int r = 0; r < 4; ++r)
          dst[ms * 16 + nt * 4 + r] = o[ms][nt][r];
    ml[(qwave * 64 + lane) * 2 + 0] = l_acc[0];
    ml[(qwave * 64 + lane) * 2 + 1] = l_acc[1];
  }
  __syncthreads();
  if (half == 1) return;
  {
    const float* src = mo + (qwave * 64 + lane) * 32;
#pragma unroll
    for (int ms = 0; ms < 2; ++ms)
#pragma unroll
      for (int nt = 0; nt < 4; ++nt)
#pragma unroll
        for (int r = 0; r < 4; ++r)
          o[ms][nt][r] += src[ms * 16 + nt * 4 + r];
    l_acc[0] += ml[(qwave * 64 + lane) * 2 + 0];
    l_acc[1] += ml[(qwave * 64 + lane) * 2 + 1];
  }

  // epilogue: reduce l across the 4 quads (once), normalize, store
#pragma unroll
  for (int ms = 0; ms < 2; ++ms) {
    float sum = l_acc[ms];
    sum += __shfl_xor(sum, 16);
    sum += __shfl_xor(sum, 32);
    const float linv = 1.0f / sum;
    float lr[4];
#pragma unroll
    for (int r = 0; r < 4; ++r) lr[r] = __shfl(linv, quad * 4 + r);
#pragma unroll
    for (int r = 0; r < 4; ++r) {
      const int qo = qb0 + qwave * 32 + ms * 16 + quad * 4 + r;
      u16* op = Ob + ((size_t)b * T + qo) * D + h * 64 + l15;
#pragma unroll
      for (int nt = 0; nt < 4; ++nt)
        op[nt * 16] = f32_bf16(o[ms][nt][r] * lr[r]);
    }
  }
}

// ---------------------------------------------------------------------------
extern "C" void kernel_launch(void* const* d_in, const int* in_sizes, int n_in,
                              void* d_out, int out_size, void* d_ws, size_t ws_size,
                              hipStream_t stream) {
  const float* x  = (const float*)d_in[0];
  const float* wq = (const float*)d_in[1];
  const float* wk = (const float*)d_in[2];
  const float* wv = (const float*)d_in[3];
  const float* wo = (const float*)d_in[4];

  const int B = 4, T = 2048, D = 1024;
  const int M = B * T;  // 8192

  u16* ws = (u16*)d_ws;
  u16* xb  = ws;                         // M*D
  u16* wqb = xb  + (size_t)M * D;        // D*D (contiguous with xb: fused cast;
  u16* wkb = wqb + (size_t)D * D;        //  wq/wk/wv contiguous -> one 3072x1024 B)
  u16* wvb = wkb + (size_t)D * D;
  u16* wob = wvb + (size_t)D * D;
  u16* Qb  = wob + (size_t)D * D;        // M*D (pre-scaled by log2e/8)
  u16* Kb  = Qb  + (size_t)M * D;
  u16* Vt  = Kb  + (size_t)M * D;        // transposed V: [bh][d][t] (from GEMM)
  u16* Ob  = Vt  + (size_t)M * D;        // attention output

  (void)wkb; (void)wvb;

  // fused cast (dst regions xb..wob are contiguous)
  const int n_x = M * D / 4, n_w = D * D / 4;
  const int n_tot = n_x + 4 * n_w;
  cvt_all_kernel<<<(n_tot + 255) / 256, 256, 0, stream>>>(x, wq, wk, wv, wo,
                                                          xb, n_x, n_w);

  // fused QKV projection: 64 row-tiles x 8 col-tiles (128x384) = 512 blocks
  // (2 exact rounds); Q scaled by (1/sqrt(Dh)) * log2(e)
  gemm8p<0><<<512, 512, 0, stream>>>(
      xb, wqb, Qb, Kb, Vt, nullptr, 0.125f * 1.44269504f);

  // flash attention: 16 q-tiles x 64 bh = 1024 blocks of 512 threads,
  // key-split halves in-block, longest blocks dispatched first
  attn_kernel<<<dim3(1024), 512, 0, stream>>>(Qb, Kb, Vt, Ob, T);

  // output projection -> fp32 d_out: 64 x 4 (128x256) = 256 blocks (1 round)
  gemm8p<1><<<256, 512, 0, stream>>>(
      Ob, wob, nullptr, nullptr, nullptr, (float*)d_out, 1.0f);
}